// Round 3
// baseline (271.619 us; speedup 1.0000x reference)
//
#include <hip/hip_runtime.h>
#include <hip/hip_bf16.h>

#define KT 32
#define START_TAG 30
#define END_TAG 31

__device__ __forceinline__ float exp2f_fast(float x){ return __builtin_amdgcn_exp2f(x); }
__device__ __forceinline__ float log2f_fast(float x){ return __builtin_amdgcn_logf(x); }  // v_log_f32 = log2

// One 64-lane wave per block handles FOUR sequences: 2 lane-parallel (half h = lane>>5)
// x 2 time-interleaved chains (X, Y). Prob-domain CRF forward with exact power-of-2
// renorm every step. The two chains are software-pipelined one segment apart so each
// chain's LDS write->broadcast-read roundtrip hides under the other chain's FMA issue.
__global__ __launch_bounds__(64) void crf_nll(
    const float* __restrict__ feats,   // [B,T,K] f32
    const float* __restrict__ trans,   // [K,K]   f32, trans[next][prev]
    const int*   __restrict__ tags,    // [B,T]
    const int*   __restrict__ masks,   // [B,T]
    float* __restrict__ out, int B, int T)
{
    constexpr float L2E = 1.4426950408889634f;
    constexpr float LN2 = 0.6931471805599453f;
    const int lane = (int)threadIdx.x;
    const int k = lane & 31;
    const int h = lane >> 5;
    const int base = (int)blockIdx.x * 4;

    __shared__ float  Tl[KT * KT];     // natural-units transitions (gold lookups)
    __shared__ float4 prow[2][2][8];   // [chain][half][quad] = ahat rows

    for (int i = lane; i < KT * KT; i += 64) Tl[i] = trans[i];

    // Per-lane row of E = exp(trans). INVALID(-1e4) -> exp2(-14427) = 0 exactly.
    float E[KT];
#pragma unroll
    for (int j = 0; j < KT; ++j) E[j] = exp2f_fast(trans[k * KT + j] * L2E);
    const float E2 = exp2f_fast(trans[END_TAG * KT + k] * L2E);  // terminal row

    __syncthreads();

    // ---------- gold scores + lengths for the 4 sequences (all 64 lanes each) ----------
    float gs[4]; int Ls[4];
#pragma unroll
    for (int s = 0; s < 4; ++s) {
        int b = base + s; if (b >= B) b = B - 1;
        const int*   tg  = tags  + (size_t)b * T;
        const int*   mk  = masks + (size_t)b * T;
        const float* fbs = feats + (size_t)b * T * KT;
        float g = 0.f; int Lp = 0;
        for (int c = 0; c < T; c += 64) {
            const int t = c + lane;
            if (t < T) {
                const int mt = mk[t];
                Lp += mt;
                const int tagt  = tg[t];
                const int prev  = t ? tg[t - 1] : START_TAG;
                const int fprev = t ? mk[t - 1] : 1;
                if (mt)    g += fbs[(size_t)t * KT + tagt];           // emission
                if (fprev) g += Tl[tagt * KT + prev];                 // transition
                if (t == T - 1 && mt) g += Tl[END_TAG * KT + tagt];   // END term
            }
        }
#pragma unroll
        for (int d = 1; d < 64; d <<= 1) { g += __shfl_xor(g, d); Lp += __shfl_xor(Lp, d); }
        gs[s] = g; Ls[s] = Lp;
    }

    const int   LX = h ? Ls[1] : Ls[0];
    const int   LY = h ? Ls[3] : Ls[2];
    const float gX = h ? gs[1] : gs[0];
    const float gY = h ? gs[3] : gs[2];
    const int LmaxAll = max(max(Ls[0], Ls[1]), max(Ls[2], Ls[3]));

    int bX = base + h;     if (bX >= B) bX = B - 1;
    int bY = base + 2 + h; if (bY >= B) bY = B - 1;
    const float* fbX = feats + (size_t)bX * T * KT + k;
    const float* fbY = feats + (size_t)bY * T * KT + k;

    // ---------- init DP ----------
    const float init = (k == START_TAG) ? 1.f : 0.f;
    float aX = init, aY = init;
    int MX = 0, MY = 0;
    float* rowX = (float*)&prow[0][h][0];
    float* rowY = (float*)&prow[1][h][0];
    rowX[k] = init;
    rowY[k] = init;

    // feat pipelines, depth 4 supersteps per chain
    const int Tm1 = T - 1;
    float FcX = exp2f_fast(fbX[0] * L2E);
    float F1X = exp2f_fast(fbX[(size_t)min(1, Tm1) * KT] * L2E);
    float v2X = fbX[(size_t)min(2, Tm1) * KT];
    float v3X = fbX[(size_t)min(3, Tm1) * KT];
    float FcY = exp2f_fast(fbY[0] * L2E);
    float F1Y = exp2f_fast(fbY[(size_t)min(1, Tm1) * KT] * L2E);
    float v2Y = fbY[(size_t)min(2, Tm1) * KT];
    float v3Y = fbY[(size_t)min(3, Tm1) * KT];

    float pX[KT], pY[KT];

#define READROW(dst, rowptr)                                        \
    _Pragma("unroll")                                               \
    for (int i = 0; i < 8; ++i) {                                   \
        const float4 q = ((const float4*)(rowptr))[i];              \
        dst[4*i+0] = q.x; dst[4*i+1] = q.y;                         \
        dst[4*i+2] = q.z; dst[4*i+3] = q.w;                         \
    }

    READROW(pX, rowX)   // prologue: X's init row in flight

#pragma unroll 2
    for (int t = 0; t < LmaxAll; ++t) {
        // ---- issue Y's reads, then compute X from already-landed pX ----
        READROW(pY, rowY)
        {
            const unsigned pb = __float_as_uint(pX[0]);
            int e = (int)((pb >> 23) & 255u);
            if (e < 1 || e > 253) e = 127;
            const float r = __uint_as_float((unsigned)(254 - e) << 23);
            float a0 = 0.f, a1 = 0.f, a2 = 0.f, a3 = 0.f;
#pragma unroll
            for (int j = 0; j < KT; j += 4) {
                a0 = fmaf(E[j+0], pX[j+0], a0);
                a1 = fmaf(E[j+1], pX[j+1], a1);
                a2 = fmaf(E[j+2], pX[j+2], a2);
                a3 = fmaf(E[j+3], pX[j+3], a3);
            }
            const float val = ((a0 + a1) + (a2 + a3)) * (FcX * r);
            const bool act = t < LX;
            aX = act ? val : aX;
            MX += act ? (e - 127) : 0;
            rowX[k] = aX;
            int tn = t + 4; if (tn > Tm1) tn = Tm1;
            const float vn = fbX[(size_t)tn * KT];
            FcX = F1X; F1X = exp2f_fast(v2X * L2E); v2X = v3X; v3X = vn;
        }
        // ---- issue X's next reads (after X's write), compute Y from pY ----
        READROW(pX, rowX)
        {
            const unsigned pb = __float_as_uint(pY[0]);
            int e = (int)((pb >> 23) & 255u);
            if (e < 1 || e > 253) e = 127;
            const float r = __uint_as_float((unsigned)(254 - e) << 23);
            float a0 = 0.f, a1 = 0.f, a2 = 0.f, a3 = 0.f;
#pragma unroll
            for (int j = 0; j < KT; j += 4) {
                a0 = fmaf(E[j+0], pY[j+0], a0);
                a1 = fmaf(E[j+1], pY[j+1], a1);
                a2 = fmaf(E[j+2], pY[j+2], a2);
                a3 = fmaf(E[j+3], pY[j+3], a3);
            }
            const float val = ((a0 + a1) + (a2 + a3)) * (FcY * r);
            const bool act = t < LY;
            aY = act ? val : aY;
            MY += act ? (e - 127) : 0;
            rowY[k] = aY;
            int tn = t + 4; if (tn > Tm1) tn = Tm1;
            const float vn = fbY[(size_t)tn * KT];
            FcY = F1Y; F1Y = exp2f_fast(v2Y * L2E); v2Y = v3Y; v3Y = vn;
        }
    }
#undef READROW

    // terminal: Z = ln2 * (M + log2(sum_k ahat[k] * E2[k])) per chain
    float termX = aX * E2;
    float termY = aY * E2;
#pragma unroll
    for (int d = 1; d < 32; d <<= 1) {
        termX += __shfl_xor(termX, d);
        termY += __shfl_xor(termY, d);
    }
    const float ZX = ((float)MX + log2f_fast(termX)) * LN2;
    const float ZY = ((float)MY + log2f_fast(termY)) * LN2;

    if (k == 0) {
        const int oX = base + h, oY = base + 2 + h;
        if (oX < B) out[oX] = ZX - gX;
        if (oY < B) out[oY] = ZY - gY;
    }
}

extern "C" void kernel_launch(void* const* d_in, const int* in_sizes, int n_in,
                              void* d_out, int out_size, void* d_ws, size_t ws_size,
                              hipStream_t stream) {
    const float* feats = (const float*)d_in[0];
    const float* trans = (const float*)d_in[1];
    const int*   tags  = (const int*)d_in[2];
    const int*   masks = (const int*)d_in[3];
    float* out = (float*)d_out;

    const int B = out_size;                 // 1024
    const int T = in_sizes[2] / B;          // 512
    const int blocks = (B + 3) / 4;         // 4 sequences per 64-thread block

    hipLaunchKernelGGL(crf_nll, dim3(blocks), dim3(64), 0, stream,
                       feats, trans, tags, masks, out, B, T);
}

// Round 4
// 190.348 us; speedup vs baseline: 1.4270x; 1.4270x over previous
//
#include <hip/hip_runtime.h>
#include <hip/hip_bf16.h>

#define KT 32
#define START_TAG 30
#define END_TAG 31
#define NT 32   // timesteps per staged feat tile

__device__ __forceinline__ float exp2f_fast(float x){ return __builtin_amdgcn_exp2f(x); }
__device__ __forceinline__ float log2f_fast(float x){ return __builtin_amdgcn_logf(x); }  // v_log_f32 = log2

// One 64-lane wave per block, TWO sequences (half h = lane>>5, tag k = lane&31).
// Prob-domain CRF forward with exact power-of-2 renorm (keyed off p[0]'s exponent).
// Feats are staged through double-buffered 32-step LDS tiles: coalesced
// global_load_dwordx4 at tile start (T14 issue-early), ds_write_b128 at step 30
// (write-late), so the HBM latency dependency is ~30 steps deep by construction.
__global__ __launch_bounds__(64) void crf_nll(
    const float* __restrict__ feats,   // [B,T,K] f32
    const float* __restrict__ trans,   // [K,K]   f32, trans[next][prev]
    const int*   __restrict__ tags,    // [B,T]
    const int*   __restrict__ masks,   // [B,T]
    float* __restrict__ out, int B, int T)
{
    constexpr float L2E = 1.4426950408889634f;
    constexpr float LN2 = 0.6931471805599453f;
    const int lane = (int)threadIdx.x;
    const int k = lane & 31;
    const int h = lane >> 5;
    int b = (int)blockIdx.x * 2 + h;
    const bool bvalid = (b < B);
    if (!bvalid) b = B - 1;

    __shared__ float  Tl[KT * KT];                       // transitions (gold lookups)
    __shared__ float4 prow[2][8];                        // ahat row per half
    __shared__ __align__(16) float ftile[2][2][NT][KT];  // [buf][half][row][k]

    for (int i = lane; i < KT * KT; i += 64) Tl[i] = trans[i];

    // Per-lane row of E = exp(trans). INVALID(-1e4) -> 0 exactly.
    float E[KT];
#pragma unroll
    for (int j = 0; j < KT; ++j) E[j] = exp2f_fast(trans[k * KT + j] * L2E);
    const float E2 = exp2f_fast(trans[END_TAG * KT + k] * L2E);

    __syncthreads();

    // ---------- feat tile machinery ----------
    int b0 = (int)blockIdx.x * 2;     if (b0 >= B) b0 = B - 1;
    int b1 = (int)blockIdx.x * 2 + 1; if (b1 >= B) b1 = B - 1;
    const float4* f40 = (const float4*)(feats + (size_t)b0 * T * KT);
    const float4* f41 = (const float4*)(feats + (size_t)b1 * T * KT);
    float4 R[8];
    // tile ti = timesteps [ti*32, ti*32+32) = 256 float4s per sequence
#define TLOAD(ti) { const int o = (ti) * 256 + lane;                          \
    R[0]=f40[o]; R[1]=f40[o+64]; R[2]=f40[o+128]; R[3]=f40[o+192];            \
    R[4]=f41[o]; R[5]=f41[o+64]; R[6]=f41[o+128]; R[7]=f41[o+192]; }
#define TWRITE(buf) { float4* w0 = (float4*)&ftile[buf][0][0][0];             \
    float4* w1 = (float4*)&ftile[buf][1][0][0];                               \
    w0[lane]=R[0]; w0[lane+64]=R[1]; w0[lane+128]=R[2]; w0[lane+192]=R[3];    \
    w1[lane]=R[4]; w1[lane+64]=R[5]; w1[lane+128]=R[6]; w1[lane+192]=R[7]; }
#define FEAT(t) ftile[((t) >> 5) & 1][h][(t) & 31][k]

    TLOAD(0)   // overlap tile-0 fetch with the gold phase

    // ---------- gold score + length ----------
    const int*   tg = tags  + (size_t)b * T;
    const int*   mk = masks + (size_t)b * T;
    const float* fb = feats + (size_t)b * T * KT;
    float g = 0.f;
    int   Lp = 0;
    for (int c = 0; c < T; c += 32) {
        const int t  = c + k;
        const int mt = mk[t];
        Lp += mt;
        const int tagt  = tg[t];
        const int prev  = t ? tg[t - 1] : START_TAG;
        const int fprev = t ? mk[t - 1] : 1;
        if (mt)    g += fb[(size_t)t * KT + tagt];
        if (fprev) g += Tl[tagt * KT + prev];
        if (t == T - 1 && mt) g += Tl[END_TAG * KT + tagt];
    }
#pragma unroll
    for (int d = 1; d < 32; d <<= 1) { g += __shfl_xor(g, d); Lp += __shfl_xor(Lp, d); }
    const int L    = Lp;
    const int Lmax = max(L, __shfl_xor(L, 32));

    // prologue staging: tile0 -> buf0, tile1 -> buf1
    TWRITE(0)
    const int ntiles = T >> 5;        // T assumed multiple of 32 (T=512)
    if (ntiles > 1) { TLOAD(1) TWRITE(1) }

    // ---------- init DP ----------
    const float init = (k == START_TAG) ? 1.f : 0.f;
    float ahat = init;
    int M = 0;
    ((float*)prow)[lane] = init;

    // feat register pipeline, depth 2 (LDS-backed)
    float Fc = exp2f_fast(FEAT(0) * L2E);
    float f1 = FEAT(1);
    float f2 = FEAT(2);

    const int nact = (Lmax + NT - 1) >> 5;
    for (int n = 0; n < nact; ++n) {
        const int tb = n << 5;
#pragma unroll
        for (int ti_ = 0; ti_ < NT; ++ti_) {
            const int t = tb + ti_;
            if (ti_ == 0)  { const int nx = n + 2; if (nx < ntiles) TLOAD(nx) }
            // broadcast-read this half's ahat row (8x ds_read_b128, conflict-free)
            float p[KT];
#pragma unroll
            for (int i = 0; i < 8; ++i) {
                const float4 q = prow[h][i];
                p[4*i+0] = q.x; p[4*i+1] = q.y; p[4*i+2] = q.z; p[4*i+3] = q.w;
            }
            // exact power-of-2 renorm from p[0]'s exponent (off the critical tail)
            const unsigned pb = __float_as_uint(p[0]);
            int e = (int)((pb >> 23) & 255u);
            if (e < 1 || e > 253) e = 127;
            const float Fcr = Fc * __uint_as_float((unsigned)(254 - e) << 23);
            float a0 = 0.f, a1 = 0.f, a2 = 0.f, a3 = 0.f;
#pragma unroll
            for (int j = 0; j < KT; j += 4) {
                a0 = fmaf(E[j+0], p[j+0], a0);
                a1 = fmaf(E[j+1], p[j+1], a1);
                a2 = fmaf(E[j+2], p[j+2], a2);
                a3 = fmaf(E[j+3], p[j+3], a3);
            }
            const float val = ((a0 + a1) + (a2 + a3)) * Fcr;
            const bool act = t < L;
            ahat = act ? val : ahat;
            M   += act ? (e - 127) : 0;
            ((float*)prow)[lane] = ahat;
            if (ti_ == 30) { const int nx = n + 2; if (nx < ntiles) TWRITE(n & 1) }
            // rotate feat pipeline: read raw feat(t+2) from LDS, cook feat(t+1)
            const float fnew = FEAT(t + 2);   // stale-read beyond T is discarded via act
            Fc = exp2f_fast(f1 * L2E);
            f1 = f2;
            f2 = fnew;
        }
    }

    // terminal: Z = ln2 * (M + log2(sum_k ahat[k] * E2[k]))
    float term = ahat * E2;
#pragma unroll
    for (int d = 1; d < 32; d <<= 1) term += __shfl_xor(term, d);
    const float Z = ((float)M + log2f_fast(term)) * LN2;

    if (k == 0 && bvalid) out[b] = Z - g;
#undef TLOAD
#undef TWRITE
#undef FEAT
}

extern "C" void kernel_launch(void* const* d_in, const int* in_sizes, int n_in,
                              void* d_out, int out_size, void* d_ws, size_t ws_size,
                              hipStream_t stream) {
    const float* feats = (const float*)d_in[0];
    const float* trans = (const float*)d_in[1];
    const int*   tags  = (const int*)d_in[2];
    const int*   masks = (const int*)d_in[3];
    float* out = (float*)d_out;

    const int B = out_size;                 // 1024
    const int T = in_sizes[2] / B;          // 512
    const int blocks = (B + 1) / 2;         // 2 sequences per 64-thread block

    hipLaunchKernelGGL(crf_nll, dim3(blocks), dim3(64), 0, stream,
                       feats, trans, tags, masks, out, B, T);
}